// Round 20
// baseline (155.671 us; speedup 1.0000x reference)
//
#include <hip/hip_runtime.h>
#include <hip/hip_bf16.h>

// Problem constants (from reference)
#define N_NODES 100000
#define N_EDGES 400000
#define IN_F    128
#define HID     1024
#define OUT_F   64
#define BUCKET_CAP 24   // deg ~ Poisson(4); P(deg>24) ~ 1e-9 over all nodes

typedef __attribute__((ext_vector_type(8))) short short8;
typedef __attribute__((ext_vector_type(4))) float floatx4;

__device__ inline unsigned short f2bf(float f) {   // RNE fp32 -> bf16
    unsigned int u = __float_as_uint(f);
    unsigned int r = u + 0x7FFF + ((u >> 16) & 1);
    return (unsigned short)(r >> 16);
}

// packed RNE cvt: 2 fp32 -> 1 u32 of 2 bf16
__device__ inline unsigned int cvtpk(float a, float b) {
    union { __hip_bfloat162 h; unsigned int u; } v;
    v.h = __float22bfloat162_rn(float2{a, b});
    return v.u;
}

__device__ inline float bf2f(unsigned int lo16) {  // bf16 (low 16 bits) -> fp32
    return __uint_as_float(lo16 << 16);
}

// async global->LDS, 16B per lane; LDS dest = uniform base + lane*16
__device__ __forceinline__ void gload_lds16(const void* g, void* l) {
    __builtin_amdgcn_global_load_lds(
        (const __attribute__((address_space(1))) void*)g,
        (__attribute__((address_space(3))) void*)l, 16, 0, 0);
}

// ---------------- fused setup: convert_xb | convert_wstream | deg_accum | pair_fill ----
// Four mutually independent passes merged into one launch (block-range dispatch).
// deg/cnt are pre-zeroed by hipMemsetAsync; deg accumulates sum(w) only.
// Pairs store (src, RAW w) -- norm is computed at consumption time as
// rsqrtf(deg[s]+1) * w * rsqrtf(deg[d]+1), identical arithmetic, which removes
// the deg dependency and lets the pair scatter run inside setup.
#define XB_BLOCKS   6250
#define WSB_BLOCKS  768
#define DEG_BLOCKS  1563
#define PAIR_BLOCKS 1563

__global__ __launch_bounds__(256) void setup_kernel(
    const float* __restrict__ x, unsigned short* __restrict__ xb,
    const float* __restrict__ W1, const float* __restrict__ W2,
    unsigned short* __restrict__ S,
    const int* __restrict__ src, const int* __restrict__ dst,
    const float* __restrict__ ew,
    float* __restrict__ deg, int* __restrict__ cnt, int2* __restrict__ pairs)
{
    int b = blockIdx.x;
    int tid = threadIdx.x;
    if (b < XB_BLOCKS) {
        long i = (long)b * 256 + tid;
        float4 a = ((const float4*)x)[i * 2];
        float4 c = ((const float4*)x)[i * 2 + 1];
        ((uint4*)xb)[i] = make_uint4(cvtpk(a.x, a.y), cvtpk(a.z, a.w),
                                     cvtpk(c.x, c.y), cvtpk(c.z, c.w));
    } else if (b < XB_BLOCKS + WSB_BLOCKS) {
        // W fragment stream. Per hid-chunk c (16 chunks): 24 frags x 512 shorts,
        // lane-ordered. W1 frags (f<16): K=32 A-frags. W2 frags (f>=16): custom
        // k-slot permutation hid(j) = kb*32 + (j>>2)*16 + lq*4 + (j&3) so GEMM2's
        // B-operand is exactly GEMM1's D output (in registers).
        int idx = b - XB_BLOCKS;           // 0..767
        int c = idx / 48;                  // 0..15
        int r = (idx % 48) * 256 + tid;    // 0..12287
        int f = r >> 9;
        int l = (r >> 3) & 63;
        int j = r & 7;
        float v;
        if (f < 16) {
            int nt = f >> 2, kt = f & 3;
            int hid = c * 64 + nt * 16 + (l & 15);
            int k   = kt * 32 + (l >> 4) * 8 + j;
            v = W1[(long)k * HID + hid];
        } else {
            int f2 = f - 16;
            int kb = f2 >> 2, nt2 = f2 & 3;
            int kh = c * 64 + kb * 32 + (j >> 2) * 16 + (l >> 4) * 4 + (j & 3);
            int oc = nt2 * 16 + (l & 15);
            v = W2[(long)kh * OUT_F + oc];
        }
        S[(long)c * 12288 + r] = f2bf(v);
    } else if (b < XB_BLOCKS + WSB_BLOCKS + DEG_BLOCKS) {
        int e = (b - XB_BLOCKS - WSB_BLOCKS) * 256 + tid;
        if (e < N_EDGES) atomicAdd(&deg[dst[e]], ew[e]);
    } else {
        int e = (b - XB_BLOCKS - WSB_BLOCKS - DEG_BLOCKS) * 256 + tid;
        if (e < N_EDGES) {
            int s = src[e];
            int d = dst[e];
            int slot = atomicAdd(&cnt[d], 1);
            if (slot < BUCKET_CAP)
                pairs[(long)d * BUCKET_CAP + slot] = make_int2(s, __float_as_int(ew[e]));
        }
    }
}

// out[d][0:64] (fp32) = (1/(deg[d]+1)) * t[d] + sum norm*t[src] + bias ; QUARTER-wave/node
// norm computed on the fly: rsqrt(deg[s]+1) * w * di
__global__ __launch_bounds__(256) void gather64_kernel(
    const int2* __restrict__ pairs, const int* __restrict__ cnt,
    const float* __restrict__ deg, const unsigned short* __restrict__ tb,
    const float* __restrict__ bias, float* __restrict__ out)
{
    int node = blockIdx.x * 16 + (threadIdx.x >> 4);  // grid*16 == N exactly
    int l = threadIdx.x & 15;                         // 4 cols per lane
    float di = rsqrtf(deg[node] + 1.0f);
    float s = di * di;
    uint2 tv = ((const uint2*)(tb + (long)node * OUT_F))[l];
    float4 bb = ((const float4*)bias)[l];
    float4 acc;
    acc.x = bf2f(tv.x & 0xffffu) * s + bb.x;
    acc.y = bf2f(tv.x >> 16) * s + bb.y;
    acc.z = bf2f(tv.y & 0xffffu) * s + bb.z;
    acc.w = bf2f(tv.y >> 16) * s + bb.w;
    int c = cnt[node]; c = c < BUCKET_CAP ? c : BUCKET_CAP;
    const int2* p = pairs + (long)node * BUCKET_CAP;
    int j = 0;
    for (; j + 4 <= c; j += 4) {
        int4 q01 = *(const int4*)(p + j);
        int4 q23 = *(const int4*)(p + j + 2);
        float g0 = deg[q01.x], g1 = deg[q01.z], g2 = deg[q23.x], g3 = deg[q23.z];
        uint2 u0 = ((const uint2*)(tb + (long)q01.x * OUT_F))[l];
        uint2 u1 = ((const uint2*)(tb + (long)q01.z * OUT_F))[l];
        uint2 u2 = ((const uint2*)(tb + (long)q23.x * OUT_F))[l];
        uint2 u3 = ((const uint2*)(tb + (long)q23.z * OUT_F))[l];
        float n0 = rsqrtf(g0 + 1.0f) * __int_as_float(q01.y) * di;
        float n1 = rsqrtf(g1 + 1.0f) * __int_as_float(q01.w) * di;
        float n2 = rsqrtf(g2 + 1.0f) * __int_as_float(q23.y) * di;
        float n3 = rsqrtf(g3 + 1.0f) * __int_as_float(q23.w) * di;
        acc.x += n0 * bf2f(u0.x & 0xffffu) + n1 * bf2f(u1.x & 0xffffu)
               + n2 * bf2f(u2.x & 0xffffu) + n3 * bf2f(u3.x & 0xffffu);
        acc.y += n0 * bf2f(u0.x >> 16) + n1 * bf2f(u1.x >> 16)
               + n2 * bf2f(u2.x >> 16) + n3 * bf2f(u3.x >> 16);
        acc.z += n0 * bf2f(u0.y & 0xffffu) + n1 * bf2f(u1.y & 0xffffu)
               + n2 * bf2f(u2.y & 0xffffu) + n3 * bf2f(u3.y & 0xffffu);
        acc.w += n0 * bf2f(u0.y >> 16) + n1 * bf2f(u1.y >> 16)
               + n2 * bf2f(u2.y >> 16) + n3 * bf2f(u3.y >> 16);
    }
    for (; j < c; j++) {
        int2 pp = p[j];
        float nv = rsqrtf(deg[pp.x] + 1.0f) * __int_as_float(pp.y) * di;
        uint2 u = ((const uint2*)(tb + (long)pp.x * OUT_F))[l];
        acc.x += nv * bf2f(u.x & 0xffffu);
        acc.y += nv * bf2f(u.x >> 16);
        acc.z += nv * bf2f(u.y & 0xffffu);
        acc.w += nv * bf2f(u.y >> 16);
    }
    ((float4*)(out + (long)node * OUT_F))[l] = acc;
}

// ---------------- fused gather128 + MFMA MLP ----------------
// tb = bf16( relu( (A_norm @ xb) @ W1 + b1 ) @ W2 )
// Layer-1 aggregation fused into fragment construction (R19 structure); norm
// computed on the fly from (src, w) pairs. MLP core = R11-exact.

__global__ __launch_bounds__(512, 2) void fused_mlp_mfma_kernel(
    const int2* __restrict__ pairs, const int* __restrict__ cnt,
    const float* __restrict__ deg, const unsigned short* __restrict__ xb,
    const unsigned short* __restrict__ Wstream,
    const float* __restrict__ b1, unsigned short* __restrict__ Tb, int M)
{
    __shared__ unsigned short Wbuf[2][12288];   // 2 x 24KB W-fragment chunk

    const int tid = threadIdx.x;
    const int w   = tid >> 6;
    const int l   = tid & 63;
    const int lr  = l & 15;
    const int lq  = l >> 4;
    const long row0 = (long)blockIdx.x * 256 + w * 32;

    // ---- prologue: stage chunk 0 into buf 0 (DMA overlaps the gather below) ----
    {
        const unsigned short* g = Wstream + (long)(w * 3) * 512 + l * 8;
        unsigned short* d = &Wbuf[0][(w * 3) * 512];
        #pragma unroll
        for (int s = 0; s < 3; s++)
            gload_lds16(g + s * 512, d + s * 512);
    }

    // ---- gather layer-1 aggregation directly into X B-fragments ----
    short8 bx[2][4];
    #pragma unroll
    for (int rt = 0; rt < 2; rt++) {
        long row = row0 + rt * 16 + lr;
        if (row < M) {
            float facc[4][8];
            float di = rsqrtf(deg[row] + 1.0f);
            float s = di * di;
            const uint4* xrow = (const uint4*)(xb + row * IN_F);
            #pragma unroll
            for (int kt = 0; kt < 4; kt++) {
                uint4 u = xrow[kt * 4 + lq];
                facc[kt][0] = bf2f(u.x & 0xffffu) * s; facc[kt][1] = bf2f(u.x >> 16) * s;
                facc[kt][2] = bf2f(u.y & 0xffffu) * s; facc[kt][3] = bf2f(u.y >> 16) * s;
                facc[kt][4] = bf2f(u.z & 0xffffu) * s; facc[kt][5] = bf2f(u.z >> 16) * s;
                facc[kt][6] = bf2f(u.w & 0xffffu) * s; facc[kt][7] = bf2f(u.w >> 16) * s;
            }
            int c = cnt[row]; c = c < BUCKET_CAP ? c : BUCKET_CAP;
            const int2* p = pairs + (long)row * BUCKET_CAP;
            for (int j = 0; j < c; j++) {
                int2 pp = p[j];
                float nv = rsqrtf(deg[pp.x] + 1.0f) * __int_as_float(pp.y) * di;
                const uint4* srow = (const uint4*)(xb + (long)pp.x * IN_F);
                #pragma unroll
                for (int kt = 0; kt < 4; kt++) {
                    uint4 u = srow[kt * 4 + lq];
                    facc[kt][0] += nv * bf2f(u.x & 0xffffu); facc[kt][1] += nv * bf2f(u.x >> 16);
                    facc[kt][2] += nv * bf2f(u.y & 0xffffu); facc[kt][3] += nv * bf2f(u.y >> 16);
                    facc[kt][4] += nv * bf2f(u.z & 0xffffu); facc[kt][5] += nv * bf2f(u.z >> 16);
                    facc[kt][6] += nv * bf2f(u.w & 0xffffu); facc[kt][7] += nv * bf2f(u.w >> 16);
                }
            }
            #pragma unroll
            for (int kt = 0; kt < 4; kt++)
                #pragma unroll
                for (int i = 0; i < 8; i++)
                    bx[rt][kt][i] = (short)f2bf(facc[kt][i]);
        } else {
            #pragma unroll
            for (int kt = 0; kt < 4; kt++)
                #pragma unroll
                for (int i = 0; i < 8; i++)
                    bx[rt][kt][i] = 0;
        }
    }

    __syncthreads();   // implicit vmcnt(0): buf0 staged (long since landed)

    floatx4 tacc[2][4];
    #pragma unroll
    for (int rt = 0; rt < 2; rt++)
        #pragma unroll
        for (int nt = 0; nt < 4; nt++)
            tacc[rt][nt] = (floatx4)0.0f;

    for (int c = 0; c < 16; c++) {
        const unsigned short* Wb = &Wbuf[c & 1][0];

        // ---- stage chunk c+1 into other buffer (drained by end-of-chunk barrier) ----
        if (c < 15) {
            const unsigned short* g = Wstream + (long)(c + 1) * 12288 + (long)(w * 3) * 512 + l * 8;
            unsigned short* d = &Wbuf[(c + 1) & 1][(w * 3) * 512];
            #pragma unroll
            for (int s = 0; s < 3; s++)
                gload_lds16(g + s * 512, d + s * 512);
        }

        // ---- two halves: each = GEMM1 over 2 nt-blocks + in-reg cvt + GEMM2 kb=h ----
        #pragma unroll
        for (int h = 0; h < 2; h++) {
            floatx4 hacc[2][2];
            #pragma unroll
            for (int rt = 0; rt < 2; rt++)
                #pragma unroll
                for (int n = 0; n < 2; n++)
                    hacc[rt][n] = (floatx4)0.0f;

            // GEMM1: hacc[rt][n] = H[xrow=lr][hid=(2h+n)*16 + lq*4 + r]
            #pragma unroll
            for (int n = 0; n < 2; n++) {
                const int nt = h * 2 + n;
                short8 w1f[4];
                #pragma unroll
                for (int kt = 0; kt < 4; kt++)
                    w1f[kt] = *(const short8*)(Wb + (nt * 4 + kt) * 512 + l * 8);
                #pragma unroll
                for (int kt = 0; kt < 4; kt++) {
                    hacc[0][n] = __builtin_amdgcn_mfma_f32_16x16x32_bf16(w1f[kt], bx[0][kt], hacc[0][n], 0, 0, 0);
                    hacc[1][n] = __builtin_amdgcn_mfma_f32_16x16x32_bf16(w1f[kt], bx[1][kt], hacc[1][n], 0, 0, 0);
                }
            }

            // bias + relu + cvt -> GEMM2 B-fragment, entirely in registers.
            floatx4 bb0 = *(const floatx4*)(b1 + c * 64 + (h * 2 + 0) * 16 + lq * 4);
            floatx4 bb1 = *(const floatx4*)(b1 + c * 64 + (h * 2 + 1) * 16 + lq * 4);
            short8 hf[2];
            #pragma unroll
            for (int rt = 0; rt < 2; rt++) {
                #pragma unroll
                for (int r = 0; r < 4; r++) {
                    hf[rt][r]     = (short)f2bf(fmaxf(hacc[rt][0][r] + bb0[r], 0.0f));
                    hf[rt][r + 4] = (short)f2bf(fmaxf(hacc[rt][1][r] + bb1[r], 0.0f));
                }
            }

            // GEMM2 (kb = h): tacc[rt][nt2] += W2frag(kb,nt2) x hf[rt]
            #pragma unroll
            for (int nt2 = 0; nt2 < 4; nt2++) {
                short8 w2f = *(const short8*)(Wb + (16 + h * 4 + nt2) * 512 + l * 8);
                tacc[0][nt2] = __builtin_amdgcn_mfma_f32_16x16x32_bf16(w2f, hf[0], tacc[0][nt2], 0, 0, 0);
                tacc[1][nt2] = __builtin_amdgcn_mfma_f32_16x16x32_bf16(w2f, hf[1], tacc[1][nt2], 0, 0, 0);
            }
        }

        // ---- end of chunk: drain stage (implicit vmcnt(0)) + join waves ----
        if (c < 15) __syncthreads();
    }

    // ---- store T as bf16: lane lr owns row; lq*4..+3 consecutive ocol -> uint2 ----
    #pragma unroll
    for (int rt = 0; rt < 2; rt++) {
        long row = row0 + rt * 16 + lr;
        if (row < M) {
            #pragma unroll
            for (int nt = 0; nt < 4; nt++) {
                unsigned int q0 = (unsigned int)f2bf(tacc[rt][nt][0]) | ((unsigned int)f2bf(tacc[rt][nt][1]) << 16);
                unsigned int q1 = (unsigned int)f2bf(tacc[rt][nt][2]) | ((unsigned int)f2bf(tacc[rt][nt][3]) << 16);
                *(uint2*)(Tb + row * OUT_F + nt * 16 + lq * 4) = make_uint2(q0, q1);
            }
        }
    }
}

// ---------------- launch ----------------

extern "C" void kernel_launch(void* const* d_in, const int* in_sizes, int n_in,
                              void* d_out, int out_size, void* d_ws, size_t ws_size,
                              hipStream_t stream) {
    const float* x   = (const float*)d_in[0];                 // [N, 128]
    const int*   src = (const int*)d_in[1];                   // edge_index[0]
    const int*   dst = ((const int*)d_in[1]) + N_EDGES;       // edge_index[1]
    const float* ew  = (const float*)d_in[2];                 // [E]
    const float* W1  = (const float*)d_in[3];                 // [128, 1024]
    const float* b1  = (const float*)d_in[4];                 // [1024]
    const float* W2  = (const float*)d_in[5];                 // [1024, 64]
    const float* b2  = (const float*)d_in[6];                 // [64]
    float* out = (float*)d_out;                               // [N, 64]

    // workspace layout (float offsets), ~60 MB total
    float* ws     = (float*)d_ws;
    float* deg    = ws;                                        // 100096 (sum w; use deg+1)
    int*   cnt    = (int*)(ws + 100096);                       // 100096
    int2*  pairs  = (int2*)(ws + 200192);                      // 2.4M int2 = 4.8M f
    unsigned short* xb  = (unsigned short*)(ws + 5000192);     // N*128 bf16 = 6.4M f
    unsigned short* tb  = (unsigned short*)(ws + 11400192);    // N*64 bf16 = 3.2M f
    unsigned short* wstream = (unsigned short*)(ws + 14600192);// 196608 shorts

    const int B = 256;

    // 1. zero deg + cnt (adjacent region) in one memset node
    hipMemsetAsync(ws, 0, 200192 * sizeof(float), stream);

    // 2. fused setup: x->bf16 | W fragment stream | deg accumulation | pair scatter
    setup_kernel<<<XB_BLOCKS + WSB_BLOCKS + DEG_BLOCKS + PAIR_BLOCKS, B, 0, stream>>>(
        x, xb, W1, W2, wstream, src, dst, ew, deg, cnt, pairs);

    // 3. fused: layer-1 gather + MLP -> tb = bf16(relu((A@xb)@W1+b1)@W2)
    fused_mlp_mfma_kernel<<<(N_NODES + 255) / 256, 512, 0, stream>>>(
        pairs, cnt, deg, xb, wstream, b1, tb, N_NODES);

    // 4. layer-2 aggregation (gather, quarter-wave): out = A_norm @ tb + b2
    gather64_kernel<<<N_NODES / 16, 256, 0, stream>>>(pairs, cnt, deg, tb, b2, out);
}

// Round 21
// 152.262 us; speedup vs baseline: 1.0224x; 1.0224x over previous
//
#include <hip/hip_runtime.h>
#include <hip/hip_bf16.h>

// Problem constants (from reference)
#define N_NODES 100000
#define N_EDGES 400000
#define IN_F    128
#define HID     1024
#define OUT_F   64
#define BUCKET_CAP 24   // deg ~ Poisson(4); P(deg>24) ~ 1e-9 over all nodes

typedef __attribute__((ext_vector_type(8))) short short8;
typedef __attribute__((ext_vector_type(4))) float floatx4;

__device__ inline unsigned short f2bf(float f) {   // RNE fp32 -> bf16
    unsigned int u = __float_as_uint(f);
    unsigned int r = u + 0x7FFF + ((u >> 16) & 1);
    return (unsigned short)(r >> 16);
}

// packed RNE cvt: 2 fp32 -> 1 u32 of 2 bf16
__device__ inline unsigned int cvtpk(float a, float b) {
    union { __hip_bfloat162 h; unsigned int u; } v;
    v.h = __float22bfloat162_rn(float2{a, b});
    return v.u;
}

__device__ inline float bf2f(unsigned int lo16) {  // bf16 (low 16 bits) -> fp32
    return __uint_as_float(lo16 << 16);
}

// async global->LDS, 16B per lane; LDS dest = uniform base + lane*16
__device__ __forceinline__ void gload_lds16(const void* g, void* l) {
    __builtin_amdgcn_global_load_lds(
        (const __attribute__((address_space(1))) void*)g,
        (__attribute__((address_space(3))) void*)l, 16, 0, 0);
}

// ---------------- fused setup: convert_xb | convert_wstream | deg_accum ----------------
// deg/cnt are pre-zeroed by hipMemsetAsync; deg accumulates sum(w) only and every
// consumer uses (deg + 1.0f) for the self-loop.
#define XB_BLOCKS  6250
#define WSB_BLOCKS 768
#define DEG_BLOCKS 1563

__global__ __launch_bounds__(256) void setup_kernel(
    const float* __restrict__ x, unsigned short* __restrict__ xb,
    const float* __restrict__ W1, const float* __restrict__ W2,
    unsigned short* __restrict__ S,
    const int* __restrict__ dst, const float* __restrict__ ew,
    float* __restrict__ deg)
{
    int b = blockIdx.x;
    int tid = threadIdx.x;
    if (b < XB_BLOCKS) {
        long i = (long)b * 256 + tid;
        float4 a = ((const float4*)x)[i * 2];
        float4 c = ((const float4*)x)[i * 2 + 1];
        ((uint4*)xb)[i] = make_uint4(cvtpk(a.x, a.y), cvtpk(a.z, a.w),
                                     cvtpk(c.x, c.y), cvtpk(c.z, c.w));
    } else if (b < XB_BLOCKS + WSB_BLOCKS) {
        // W fragment stream. Per hid-chunk c (16 chunks): 24 frags x 512 shorts,
        // lane-ordered. W1 frags (f<16): K=32 A-frags. W2 frags (f>=16): custom
        // k-slot permutation hid(j) = kb*32 + (j>>2)*16 + lq*4 + (j&3) so GEMM2's
        // B-operand is exactly GEMM1's D output (in registers).
        int idx = b - XB_BLOCKS;           // 0..767
        int c = idx / 48;                  // 0..15
        int r = (idx % 48) * 256 + tid;    // 0..12287
        int f = r >> 9;
        int l = (r >> 3) & 63;
        int j = r & 7;
        float v;
        if (f < 16) {
            int nt = f >> 2, kt = f & 3;
            int hid = c * 64 + nt * 16 + (l & 15);
            int k   = kt * 32 + (l >> 4) * 8 + j;
            v = W1[(long)k * HID + hid];
        } else {
            int f2 = f - 16;
            int kb = f2 >> 2, nt2 = f2 & 3;
            int kh = c * 64 + kb * 32 + (j >> 2) * 16 + (l >> 4) * 4 + (j & 3);
            int oc = nt2 * 16 + (l & 15);
            v = W2[(long)kh * OUT_F + oc];
        }
        S[(long)c * 12288 + r] = f2bf(v);
    } else {
        int e = (b - XB_BLOCKS - WSB_BLOCKS) * 256 + tid;
        if (e < N_EDGES) atomicAdd(&deg[dst[e]], ew[e]);
    }
}

// pairs[d][slot] = (src[e], norm[e]); rsqrt + self-loop(+1) folded in
__global__ void fill_pairs_kernel(const int* __restrict__ src, const int* __restrict__ dst,
                                  const float* __restrict__ w, const float* __restrict__ deg,
                                  int* __restrict__ cnt, int2* __restrict__ pairs, int E) {
    int e = blockIdx.x * blockDim.x + threadIdx.x;
    if (e < E) {
        int s = src[e];
        int d = dst[e];
        float nv = rsqrtf(deg[s] + 1.0f) * w[e] * rsqrtf(deg[d] + 1.0f);
        int slot = atomicAdd(&cnt[d], 1);
        if (slot < BUCKET_CAP)
            pairs[(long)d * BUCKET_CAP + slot] = make_int2(s, __float_as_int(nv));
    }
}

// out[d][0:64] (fp32) = (1/(deg[d]+1)) * t[d] + sum norm*t[src] + bias ; QUARTER-wave/node
__global__ __launch_bounds__(256) void gather64_kernel(
    const int2* __restrict__ pairs, const int* __restrict__ cnt,
    const float* __restrict__ deg, const unsigned short* __restrict__ tb,
    const float* __restrict__ bias, float* __restrict__ out)
{
    int node = blockIdx.x * 16 + (threadIdx.x >> 4);  // grid*16 == N exactly
    int l = threadIdx.x & 15;                         // 4 cols per lane
    float di = rsqrtf(deg[node] + 1.0f);
    float s = di * di;
    uint2 tv = ((const uint2*)(tb + (long)node * OUT_F))[l];
    float4 bb = ((const float4*)bias)[l];
    float4 acc;
    acc.x = bf2f(tv.x & 0xffffu) * s + bb.x;
    acc.y = bf2f(tv.x >> 16) * s + bb.y;
    acc.z = bf2f(tv.y & 0xffffu) * s + bb.z;
    acc.w = bf2f(tv.y >> 16) * s + bb.w;
    int c = cnt[node]; c = c < BUCKET_CAP ? c : BUCKET_CAP;
    const int2* p = pairs + (long)node * BUCKET_CAP;
    int j = 0;
    for (; j + 4 <= c; j += 4) {
        int4 q01 = *(const int4*)(p + j);
        int4 q23 = *(const int4*)(p + j + 2);
        uint2 u0 = ((const uint2*)(tb + (long)q01.x * OUT_F))[l];
        uint2 u1 = ((const uint2*)(tb + (long)q01.z * OUT_F))[l];
        uint2 u2 = ((const uint2*)(tb + (long)q23.x * OUT_F))[l];
        uint2 u3 = ((const uint2*)(tb + (long)q23.z * OUT_F))[l];
        float n0 = __int_as_float(q01.y), n1 = __int_as_float(q01.w);
        float n2 = __int_as_float(q23.y), n3 = __int_as_float(q23.w);
        acc.x += n0 * bf2f(u0.x & 0xffffu) + n1 * bf2f(u1.x & 0xffffu)
               + n2 * bf2f(u2.x & 0xffffu) + n3 * bf2f(u3.x & 0xffffu);
        acc.y += n0 * bf2f(u0.x >> 16) + n1 * bf2f(u1.x >> 16)
               + n2 * bf2f(u2.x >> 16) + n3 * bf2f(u3.x >> 16);
        acc.z += n0 * bf2f(u0.y & 0xffffu) + n1 * bf2f(u1.y & 0xffffu)
               + n2 * bf2f(u2.y & 0xffffu) + n3 * bf2f(u3.y & 0xffffu);
        acc.w += n0 * bf2f(u0.y >> 16) + n1 * bf2f(u1.y >> 16)
               + n2 * bf2f(u2.y >> 16) + n3 * bf2f(u3.y >> 16);
    }
    for (; j < c; j++) {
        int2 pp = p[j];
        float nv = __int_as_float(pp.y);
        uint2 u = ((const uint2*)(tb + (long)pp.x * OUT_F))[l];
        acc.x += nv * bf2f(u.x & 0xffffu);
        acc.y += nv * bf2f(u.x >> 16);
        acc.z += nv * bf2f(u.y & 0xffffu);
        acc.w += nv * bf2f(u.y >> 16);
    }
    ((float4*)(out + (long)node * OUT_F))[l] = acc;
}

// ---------------- fused gather128 + MFMA MLP ----------------
// tb = bf16( relu( (A_norm @ xb) @ W1 + b1 ) @ W2 )
// The layer-1 aggregation is fused INTO fragment construction: MLP lane (lr,lq)
// needs exactly uint4 chunk (kt*4+lq) of row (row0+rt*16+lr) -- so each lane
// gathers its own node's pair list directly into facc[4][8] fp32 and packs to
// bx fragments in registers. No xab buffer, no separate gather kernel; the
// gather's memory latency hides in the MLP's idle issue slots. Identical
// rounding chain to the unfused path (fp32 acc -> one bf16 cvt).
// MLP core = R11-exact (zero-shuffle GEMM2, 8 waves x 32 rows, grid 391).

__global__ __launch_bounds__(512, 2) void fused_mlp_mfma_kernel(
    const int2* __restrict__ pairs, const int* __restrict__ cnt,
    const float* __restrict__ deg, const unsigned short* __restrict__ xb,
    const unsigned short* __restrict__ Wstream,
    const float* __restrict__ b1, unsigned short* __restrict__ Tb, int M)
{
    __shared__ unsigned short Wbuf[2][12288];   // 2 x 24KB W-fragment chunk

    const int tid = threadIdx.x;
    const int w   = tid >> 6;
    const int l   = tid & 63;
    const int lr  = l & 15;
    const int lq  = l >> 4;
    const long row0 = (long)blockIdx.x * 256 + w * 32;

    // ---- prologue: stage chunk 0 into buf 0 (DMA overlaps the gather below) ----
    {
        const unsigned short* g = Wstream + (long)(w * 3) * 512 + l * 8;
        unsigned short* d = &Wbuf[0][(w * 3) * 512];
        #pragma unroll
        for (int s = 0; s < 3; s++)
            gload_lds16(g + s * 512, d + s * 512);
    }

    // ---- gather layer-1 aggregation directly into X B-fragments ----
    short8 bx[2][4];
    #pragma unroll
    for (int rt = 0; rt < 2; rt++) {
        long row = row0 + rt * 16 + lr;
        if (row < M) {
            float facc[4][8];
            float di = rsqrtf(deg[row] + 1.0f);
            float s = di * di;
            const uint4* xrow = (const uint4*)(xb + row * IN_F);
            #pragma unroll
            for (int kt = 0; kt < 4; kt++) {
                uint4 u = xrow[kt * 4 + lq];
                facc[kt][0] = bf2f(u.x & 0xffffu) * s; facc[kt][1] = bf2f(u.x >> 16) * s;
                facc[kt][2] = bf2f(u.y & 0xffffu) * s; facc[kt][3] = bf2f(u.y >> 16) * s;
                facc[kt][4] = bf2f(u.z & 0xffffu) * s; facc[kt][5] = bf2f(u.z >> 16) * s;
                facc[kt][6] = bf2f(u.w & 0xffffu) * s; facc[kt][7] = bf2f(u.w >> 16) * s;
            }
            int c = cnt[row]; c = c < BUCKET_CAP ? c : BUCKET_CAP;
            const int2* p = pairs + (long)row * BUCKET_CAP;
            for (int j = 0; j < c; j++) {
                int2 pp = p[j];
                float nv = __int_as_float(pp.y);
                const uint4* srow = (const uint4*)(xb + (long)pp.x * IN_F);
                #pragma unroll
                for (int kt = 0; kt < 4; kt++) {
                    uint4 u = srow[kt * 4 + lq];
                    facc[kt][0] += nv * bf2f(u.x & 0xffffu); facc[kt][1] += nv * bf2f(u.x >> 16);
                    facc[kt][2] += nv * bf2f(u.y & 0xffffu); facc[kt][3] += nv * bf2f(u.y >> 16);
                    facc[kt][4] += nv * bf2f(u.z & 0xffffu); facc[kt][5] += nv * bf2f(u.z >> 16);
                    facc[kt][6] += nv * bf2f(u.w & 0xffffu); facc[kt][7] += nv * bf2f(u.w >> 16);
                }
            }
            #pragma unroll
            for (int kt = 0; kt < 4; kt++)
                #pragma unroll
                for (int i = 0; i < 8; i++)
                    bx[rt][kt][i] = (short)f2bf(facc[kt][i]);
        } else {
            #pragma unroll
            for (int kt = 0; kt < 4; kt++)
                #pragma unroll
                for (int i = 0; i < 8; i++)
                    bx[rt][kt][i] = 0;
        }
    }

    __syncthreads();   // implicit vmcnt(0): buf0 staged (long since landed)

    floatx4 tacc[2][4];
    #pragma unroll
    for (int rt = 0; rt < 2; rt++)
        #pragma unroll
        for (int nt = 0; nt < 4; nt++)
            tacc[rt][nt] = (floatx4)0.0f;

    for (int c = 0; c < 16; c++) {
        const unsigned short* Wb = &Wbuf[c & 1][0];

        // ---- stage chunk c+1 into other buffer (drained by end-of-chunk barrier) ----
        if (c < 15) {
            const unsigned short* g = Wstream + (long)(c + 1) * 12288 + (long)(w * 3) * 512 + l * 8;
            unsigned short* d = &Wbuf[(c + 1) & 1][(w * 3) * 512];
            #pragma unroll
            for (int s = 0; s < 3; s++)
                gload_lds16(g + s * 512, d + s * 512);
        }

        // ---- two halves: each = GEMM1 over 2 nt-blocks + in-reg cvt + GEMM2 kb=h ----
        #pragma unroll
        for (int h = 0; h < 2; h++) {
            floatx4 hacc[2][2];
            #pragma unroll
            for (int rt = 0; rt < 2; rt++)
                #pragma unroll
                for (int n = 0; n < 2; n++)
                    hacc[rt][n] = (floatx4)0.0f;

            // GEMM1: hacc[rt][n] = H[xrow=lr][hid=(2h+n)*16 + lq*4 + r]
            #pragma unroll
            for (int n = 0; n < 2; n++) {
                const int nt = h * 2 + n;
                short8 w1f[4];
                #pragma unroll
                for (int kt = 0; kt < 4; kt++)
                    w1f[kt] = *(const short8*)(Wb + (nt * 4 + kt) * 512 + l * 8);
                #pragma unroll
                for (int kt = 0; kt < 4; kt++) {
                    hacc[0][n] = __builtin_amdgcn_mfma_f32_16x16x32_bf16(w1f[kt], bx[0][kt], hacc[0][n], 0, 0, 0);
                    hacc[1][n] = __builtin_amdgcn_mfma_f32_16x16x32_bf16(w1f[kt], bx[1][kt], hacc[1][n], 0, 0, 0);
                }
            }

            // bias + relu + cvt -> GEMM2 B-fragment, entirely in registers.
            floatx4 bb0 = *(const floatx4*)(b1 + c * 64 + (h * 2 + 0) * 16 + lq * 4);
            floatx4 bb1 = *(const floatx4*)(b1 + c * 64 + (h * 2 + 1) * 16 + lq * 4);
            short8 hf[2];
            #pragma unroll
            for (int rt = 0; rt < 2; rt++) {
                #pragma unroll
                for (int r = 0; r < 4; r++) {
                    hf[rt][r]     = (short)f2bf(fmaxf(hacc[rt][0][r] + bb0[r], 0.0f));
                    hf[rt][r + 4] = (short)f2bf(fmaxf(hacc[rt][1][r] + bb1[r], 0.0f));
                }
            }

            // GEMM2 (kb = h): tacc[rt][nt2] += W2frag(kb,nt2) x hf[rt]
            #pragma unroll
            for (int nt2 = 0; nt2 < 4; nt2++) {
                short8 w2f = *(const short8*)(Wb + (16 + h * 4 + nt2) * 512 + l * 8);
                tacc[0][nt2] = __builtin_amdgcn_mfma_f32_16x16x32_bf16(w2f, hf[0], tacc[0][nt2], 0, 0, 0);
                tacc[1][nt2] = __builtin_amdgcn_mfma_f32_16x16x32_bf16(w2f, hf[1], tacc[1][nt2], 0, 0, 0);
            }
        }

        // ---- end of chunk: drain stage (implicit vmcnt(0)) + join waves ----
        if (c < 15) __syncthreads();
    }

    // ---- store T as bf16: lane lr owns row; lq*4..+3 consecutive ocol -> uint2 ----
    #pragma unroll
    for (int rt = 0; rt < 2; rt++) {
        long row = row0 + rt * 16 + lr;
        if (row < M) {
            #pragma unroll
            for (int nt = 0; nt < 4; nt++) {
                unsigned int q0 = (unsigned int)f2bf(tacc[rt][nt][0]) | ((unsigned int)f2bf(tacc[rt][nt][1]) << 16);
                unsigned int q1 = (unsigned int)f2bf(tacc[rt][nt][2]) | ((unsigned int)f2bf(tacc[rt][nt][3]) << 16);
                *(uint2*)(Tb + row * OUT_F + nt * 16 + lq * 4) = make_uint2(q0, q1);
            }
        }
    }
}

// ---------------- launch ----------------

extern "C" void kernel_launch(void* const* d_in, const int* in_sizes, int n_in,
                              void* d_out, int out_size, void* d_ws, size_t ws_size,
                              hipStream_t stream) {
    const float* x   = (const float*)d_in[0];                 // [N, 128]
    const int*   src = (const int*)d_in[1];                   // edge_index[0]
    const int*   dst = ((const int*)d_in[1]) + N_EDGES;       // edge_index[1]
    const float* ew  = (const float*)d_in[2];                 // [E]
    const float* W1  = (const float*)d_in[3];                 // [128, 1024]
    const float* b1  = (const float*)d_in[4];                 // [1024]
    const float* W2  = (const float*)d_in[5];                 // [1024, 64]
    const float* b2  = (const float*)d_in[6];                 // [64]
    float* out = (float*)d_out;                               // [N, 64]

    // workspace layout (float offsets), ~60 MB total (xab eliminated)
    float* ws     = (float*)d_ws;
    float* deg    = ws;                                        // 100096 (sum w; use deg+1)
    int*   cnt    = (int*)(ws + 100096);                       // 100096
    int2*  pairs  = (int2*)(ws + 200192);                      // 2.4M int2 = 4.8M f
    unsigned short* xb  = (unsigned short*)(ws + 5000192);     // N*128 bf16 = 6.4M f
    unsigned short* tb  = (unsigned short*)(ws + 11400192);    // N*64 bf16 = 3.2M f
    unsigned short* wstream = (unsigned short*)(ws + 14600192);// 196608 shorts

    const int B = 256;

    // 1. zero deg + cnt (adjacent region) in one memset node
    hipMemsetAsync(ws, 0, 200192 * sizeof(float), stream);

    // 2. fused setup: x->bf16 | W fragment stream | degree accumulation
    setup_kernel<<<XB_BLOCKS + WSB_BLOCKS + DEG_BLOCKS, B, 0, stream>>>(
        x, xb, W1, W2, wstream, dst, ew, deg);

    // 3. pair-bucket fill (needs final deg)
    fill_pairs_kernel<<<(N_EDGES + B - 1) / B, B, 0, stream>>>(src, dst, ew, deg, cnt, pairs, N_EDGES);

    // 4. fused: layer-1 gather + MLP -> tb = bf16(relu((A@xb)@W1+b1)@W2)
    fused_mlp_mfma_kernel<<<(N_NODES + 255) / 256, 512, 0, stream>>>(
        pairs, cnt, deg, xb, wstream, b1, tb, N_NODES);

    // 5. layer-2 aggregation (gather, quarter-wave): out = A_norm @ tb + b2
    gather64_kernel<<<N_NODES / 16, 256, 0, stream>>>(pairs, cnt, deg, tb, b2, out);
}